// Round 5
// baseline (355.178 us; speedup 1.0000x reference)
//
#include <hip/hip_runtime.h>

#define N_NODES 100000
#define N_EDGES 1600000
#define FEAT 128
#define GEMM_BLOCKS 1563 // ceil(100000/64)
#define DEG_EPB 4096
#define DEG_BLOCKS 391   // ceil(1.6M/4096)
#define SCAT_EPB 4096
#define SCAT_BLOCKS 391
#define SCANA_CHUNK 1024
#define SCANA_BLOCKS 98  // ceil(100000/1024)
#define SCANC_BLOCKS 391 // ceil(100000/256)
#define WT_PITCH 136     // 128 + 8 pad: keeps 16B alignment, balances LDS banks

typedef __attribute__((ext_vector_type(8))) short short8;
typedef __attribute__((ext_vector_type(4))) float f32x4;

__device__ inline unsigned short f2bf(float f) {
    unsigned u = __builtin_bit_cast(unsigned, f);
    unsigned r = (u + 0x7FFFu + ((u >> 16) & 1u)) >> 16;  // RNE
    return (unsigned short)r;
}
__device__ inline float bf2f(unsigned h) {
    unsigned u = h << 16;
    return __builtin_bit_cast(float, u);
}

// ============ fused: MFMA GEMM (yb = bf16(x@W)) + per-node degree count ===========
// GEMM identical to v5 (proven). Deg blocks: 1.6M global atomicAdds on a 400KB
// L2-resident array, co-scheduled with GEMM (atomic/L2 pipe vs MFMA/HBM pipe).
__global__ __launch_bounds__(256)
void k_gemm_deg(const float* __restrict__ x, const float* __restrict__ W,
                unsigned short* __restrict__ yb,
                const int* __restrict__ col, int* __restrict__ deg) {
    int bid = blockIdx.x, tid = threadIdx.x;
    if (bid >= GEMM_BLOCKS) {
        int e0 = (bid - GEMM_BLOCKS) * DEG_EPB;
        int n = min(DEG_EPB, N_EDGES - e0);
        for (int i = tid * 4; i < n; i += 1024) {
            if (i + 3 < n) {
                int4 c4 = *(const int4*)(col + e0 + i);
                atomicAdd(&deg[c4.x], 1);
                atomicAdd(&deg[c4.y], 1);
                atomicAdd(&deg[c4.z], 1);
                atomicAdd(&deg[c4.w], 1);
            } else {
                for (int j = i; j < n; ++j) atomicAdd(&deg[col[e0 + j]], 1);
            }
        }
        return;
    }

    __shared__ unsigned short Ws[FEAT * WT_PITCH];  // Ws[f][k] = bf16(W[k][f]) = W^T
    for (int idx = tid; idx < FEAT * FEAT; idx += 256) {
        int k = idx >> 7, f = idx & 127;
        Ws[f * WT_PITCH + k] = f2bf(W[idx]);
    }
    __syncthreads();

    int lane = tid & 63;
    int m = lane & 15, quad = lane >> 4;
    int node = bid * 64 + (tid >> 6) * 16 + m;
    int ldn = node < N_NODES ? node : N_NODES - 1;  // clamp loads; stores guarded
    const float* xr = x + (size_t)ldn * FEAT + quad * 8;

    f32x4 acc[8];
#pragma unroll
    for (int nt = 0; nt < 8; ++nt) acc[nt] = (f32x4){0.f, 0.f, 0.f, 0.f};

#pragma unroll
    for (int kk = 0; kk < 4; ++kk) {
        float4 xa = *(const float4*)(xr + kk * 32);
        float4 xc = *(const float4*)(xr + kk * 32 + 4);
        short8 fx;
        fx[0] = (short)f2bf(xa.x); fx[1] = (short)f2bf(xa.y);
        fx[2] = (short)f2bf(xa.z); fx[3] = (short)f2bf(xa.w);
        fx[4] = (short)f2bf(xc.x); fx[5] = (short)f2bf(xc.y);
        fx[6] = (short)f2bf(xc.z); fx[7] = (short)f2bf(xc.w);
        const unsigned short* wp = Ws + kk * 32 + quad * 8;
#pragma unroll
        for (int nt = 0; nt < 8; ++nt) {
            short8 af = *(const short8*)(wp + (nt * 16 + m) * WT_PITCH);
            acc[nt] = __builtin_amdgcn_mfma_f32_16x16x32_bf16(af, fx, acc[nt], 0, 0, 0);
        }
    }

    // D: row = feature = nt*16 + quad*4 + r, col = node (m). 4 consecutive features
    // per lane -> one 8B store per nt (verified mapping).
    if (node < N_NODES) {
        unsigned* yp = (unsigned*)(yb + (size_t)node * FEAT);
#pragma unroll
        for (int nt = 0; nt < 8; ++nt) {
            uint2 pk;
            pk.x = (unsigned)f2bf(acc[nt][0]) | ((unsigned)f2bf(acc[nt][1]) << 16);
            pk.y = (unsigned)f2bf(acc[nt][2]) | ((unsigned)f2bf(acc[nt][3]) << 16);
            *(uint2*)(yp + nt * 8 + quad * 2) = pk;
        }
    }
}

// ============ scan A: per-1024-chunk exclusive scan of deg -> starts, chunk sums ===
__global__ __launch_bounds__(1024)
void k_scanA(const int* __restrict__ deg, int* __restrict__ starts,
             int* __restrict__ bsum) {
    __shared__ int wsum[16];
    int tid = threadIdx.x;
    int i = blockIdx.x * SCANA_CHUNK + tid;
    int v = (i < N_NODES) ? deg[i] : 0;
    int lane = tid & 63, wv = tid >> 6;
    // wave-inclusive scan
    int s = v;
#pragma unroll
    for (int off = 1; off < 64; off <<= 1) {
        int t = __shfl_up(s, off);
        if (lane >= off) s += t;
    }
    if (lane == 63) wsum[wv] = s;
    __syncthreads();
    if (tid < 16) {
        int w = wsum[tid];
#pragma unroll
        for (int off = 1; off < 16; off <<= 1) {
            int t = __shfl_up(w, off);
            if (tid >= off) w += t;
        }
        wsum[tid] = w;  // inclusive over wave sums
    }
    __syncthreads();
    int wbase = (wv == 0) ? 0 : wsum[wv - 1];
    if (i < N_NODES) starts[i] = wbase + s - v;  // chunk-local exclusive
    if (tid == 0) bsum[blockIdx.x] = wsum[15];
}

// ============ scan C: add chunk offsets, init cursor, compute dinv =================
// Each block covers 256 nodes (all in one 1024-chunk); thread 0 sums bsum[0..chunk).
__global__ __launch_bounds__(256)
void k_scanC(const int* __restrict__ deg, const int* __restrict__ bsum,
             int* __restrict__ starts, int* __restrict__ cur,
             float* __restrict__ dinv) {
    __shared__ int sb[SCANA_BLOCKS];
    __shared__ int boff;
    int tid = threadIdx.x;
    int chunk = (blockIdx.x * 256) >> 10;  // uniform per block
    if (tid < SCANA_BLOCKS) sb[tid] = bsum[tid];
    __syncthreads();
    if (tid == 0) {
        int a = 0;
        for (int j = 0; j < chunk; ++j) a += sb[j];
        boff = a;
    }
    __syncthreads();
    int i = blockIdx.x * 256 + tid;
    if (i < N_NODES) {
        int s = starts[i] + boff;
        starts[i] = s;
        cur[i] = s;
        dinv[i] = rsqrtf((float)(deg[i] + 1));  // +1 self-loop
    }
    if (blockIdx.x == 0 && tid == 0) starts[N_NODES] = N_EDGES;
}

// ============ direct scatter: src_idx[starts[c] + cur[c]++] = r ====================
// Single edge pass. 1.6M global atomics on L2-resident cur (400KB, ~16 hits per
// counter -> low contention); scattered 4B writes land in node-grouped regions.
__global__ __launch_bounds__(256)
void k_scatter(const int* __restrict__ row, const int* __restrict__ col,
               int* __restrict__ cur, int* __restrict__ src_idx) {
    int tid = threadIdx.x;
    int e0 = blockIdx.x * SCAT_EPB;
    int n = min(SCAT_EPB, N_EDGES - e0);
    for (int i = tid * 4; i < n; i += 1024) {
        if (i + 3 < n) {
            int4 c4 = *(const int4*)(col + e0 + i);
            int4 r4 = *(const int4*)(row + e0 + i);
            int p;
            p = atomicAdd(&cur[c4.x], 1); src_idx[p] = r4.x;
            p = atomicAdd(&cur[c4.y], 1); src_idx[p] = r4.y;
            p = atomicAdd(&cur[c4.z], 1); src_idx[p] = r4.z;
            p = atomicAdd(&cur[c4.w], 1); src_idx[p] = r4.w;
        } else {
            for (int j = i; j < n; ++j) {
                int p = atomicAdd(&cur[col[e0 + j]], 1);
                src_idx[p] = row[e0 + j];
            }
        }
    }
}

// ============ aggregate: out[i] = b + dinv[i]*(dinv[i]*y[i] + sum dinv[s]*y[s]) ====
// One wave per node, 25000 blocks (proven: high occupancy is the resource for this
// fetch-floor-saturated gather). Unconditional 16/8/4/1 gather groups. UNCHANGED.
#define GATHER_GROUP(D)                                             \
    {                                                               \
        unsigned v[D];                                              \
        _Pragma("unroll")                                           \
        for (int t = 0; t < (D); ++t) {                             \
            int s = __shfl(src, j + t);                             \
            v[t] = y1[(size_t)(unsigned)s * 64 + lane];             \
        }                                                           \
        _Pragma("unroll")                                           \
        for (int t = 0; t < (D); ++t) {                             \
            float d = __shfl(dvv, j + t);                           \
            a0 += d * bf2f(v[t] & 0xFFFFu);                         \
            a1 += d * bf2f(v[t] >> 16);                             \
        }                                                           \
        j += (D);                                                   \
    }

__global__ __launch_bounds__(256)
void k_agg(const unsigned short* __restrict__ yb, const int* __restrict__ starts,
           const int* __restrict__ src_idx, const float* __restrict__ dinv,
           const float* __restrict__ bias, float* __restrict__ out) {
    int node = blockIdx.x * 4 + (threadIdx.x >> 6);
    int lane = threadIdx.x & 63;
    if (node >= N_NODES) return;
    int st = starts[node], en = starts[node + 1];
    float di = dinv[node];
    const unsigned* y1 = (const unsigned*)yb;  // 2 bf16 per uint
    unsigned sv = y1[(size_t)node * 64 + lane];
    float a0 = di * bf2f(sv & 0xFFFFu);
    float a1 = di * bf2f(sv >> 16);
    for (int base = st; base < en; base += 64) {
        int nn = min(64, en - base);
        int src = 0;
        float dvv = 0.f;
        if (lane < nn) {
            src = src_idx[base + lane];
            dvv = dinv[src];
        }
        int j = 0;
        while (j + 16 <= nn) GATHER_GROUP(16)
        if (j + 8 <= nn) GATHER_GROUP(8)
        if (j + 4 <= nn) GATHER_GROUP(4)
        for (; j < nn; ++j) {
            int s = __shfl(src, j);
            float d = __shfl(dvv, j);
            unsigned v = y1[(size_t)(unsigned)s * 64 + lane];
            a0 += d * bf2f(v & 0xFFFFu);
            a1 += d * bf2f(v >> 16);
        }
    }
    float2 bb = ((const float2*)bias)[lane];
    float2 o;
    o.x = bb.x + di * a0;
    o.y = bb.y + di * a1;
    ((float2*)out)[(size_t)node * 64 + lane] = o;
}

extern "C" void kernel_launch(void* const* d_in, const int* in_sizes, int n_in,
                              void* d_out, int out_size, void* d_ws, size_t ws_size,
                              hipStream_t stream) {
    const float* x = (const float*)d_in[0];
    const float* W = (const float*)d_in[1];
    const float* b = (const float*)d_in[2];
    const int* ei = (const int*)d_in[3];
    const int* row = ei;            // edge_index[0] = source
    const int* col = ei + N_EDGES;  // edge_index[1] = target
    float* out = (float*)d_out;

    char* ws = (char*)d_ws;
    size_t off = 0;
    auto alloc = [&](size_t bytes) -> void* {
        void* p = ws + off;
        off += (bytes + 511) & ~(size_t)511;
        return p;
    };
    int* deg           = (int*)alloc((size_t)N_NODES * 4);
    int* bsum          = (int*)alloc(SCANA_BLOCKS * 4);
    int* starts        = (int*)alloc((size_t)(N_NODES + 1) * 4);
    int* cur           = (int*)alloc((size_t)N_NODES * 4);
    float* dinv        = (float*)alloc((size_t)N_NODES * 4);
    int* src_idx       = (int*)alloc((size_t)N_EDGES * 4);
    unsigned short* yb = (unsigned short*)alloc((size_t)N_NODES * FEAT * 2);

    hipMemsetAsync(deg, 0, (size_t)N_NODES * 4, stream);

    k_gemm_deg<<<GEMM_BLOCKS + DEG_BLOCKS, 256, 0, stream>>>(x, W, yb, col, deg);
    k_scanA<<<SCANA_BLOCKS, 1024, 0, stream>>>(deg, starts, bsum);
    k_scanC<<<SCANC_BLOCKS, 256, 0, stream>>>(deg, bsum, starts, cur, dinv);
    k_scatter<<<SCAT_BLOCKS, 256, 0, stream>>>(row, col, cur, src_idx);
    k_agg<<<(N_NODES + 3) / 4, 256, 0, stream>>>(yb, starts, src_idx, dinv, b, out);
}